// Round 15
// baseline (398.879 us; speedup 1.0000x reference)
//
#include <hip/hip_runtime.h>

static inline size_t align_up(size_t x, size_t a) { return (x + a - 1) & ~(a - 1); }

using bf16x8 = __attribute__((ext_vector_type(8))) short;
using f32x4 = __attribute__((ext_vector_type(4))) float;
using f32x2 = __attribute__((ext_vector_type(2))) float;

__device__ inline ushort f2bf(float x) {  // RNE float->bf16
  unsigned u = __float_as_uint(x);
  return (ushort)((u + 0x7fffu + ((u >> 16) & 1u)) >> 16);
}
__device__ inline float bf2f(ushort h) { return __uint_as_float((unsigned)h << 16); }

// decode 4 fp8(e4m3) packed in a uint, accumulate into 2 f32x2 accumulators (v_pk_add_f32)
__device__ inline void acc4v(unsigned u, f32x2* s2) {
  s2[0] += __builtin_amdgcn_cvt_pk_f32_fp8(u, false);
  s2[1] += __builtin_amdgcn_cvt_pk_f32_fp8(u, true);
}
__device__ inline void acc16v(uint4 u, f32x2* s2) {
  acc4v(u.x, s2);
  acc4v(u.y, s2 + 2);
  acc4v(u.z, s2 + 4);
  acc4v(u.w, s2 + 6);
}

// ================= bucketed CSR build =================
// buckets of 256 consecutive dst nodes; K = ceil(N/256) (<=1024)

__global__ void bhist_kernel(const int* __restrict__ ei, int* __restrict__ bcnt, int E, int K) {
  __shared__ int lh[1024];
  int t = threadIdx.x;
  for (int i = t; i < 1024; i += 256) lh[i] = 0;
  __syncthreads();
  int base = blockIdx.x * 4096;
#pragma unroll
  for (int r = 0; r < 16; ++r) {
    int e = base + r * 256 + t;
    if (e < E) atomicAdd(&lh[ei[(size_t)E + e] >> 8], 1);
  }
  __syncthreads();
  for (int i = t; i < K; i += 256)
    if (lh[i]) atomicAdd(&bcnt[i], lh[i]);
}

__global__ void bscan_kernel(const int* __restrict__ bcnt, int* __restrict__ bbase,
                             int* __restrict__ bcur, int K) {
  __shared__ int sb[1024];
  int t = threadIdx.x;  // 1024
  int v = (t < K) ? bcnt[t] : 0;
  sb[t] = v;
  __syncthreads();
  int acc = v;
  for (int d = 1; d < 1024; d <<= 1) {
    int add = (t >= d) ? sb[t - d] : 0;
    __syncthreads();
    acc += add;
    sb[t] = acc;
    __syncthreads();
  }
  if (t < K) {
    int ex = acc - v;  // exclusive
    bbase[t] = ex;
    bcur[t] = ex;
  }
}

__global__ void bscatter_kernel(const int* __restrict__ ei, int* __restrict__ bcur,
                                int2* __restrict__ ebuf, int E) {
  __shared__ int lh[1024];
  __shared__ int lbase[1024];
  int t = threadIdx.x;
  for (int i = t; i < 1024; i += 256) lh[i] = 0;
  __syncthreads();
  int base = blockIdx.x * 4096;
  int src[16], dst[16];
#pragma unroll
  for (int r = 0; r < 16; ++r) {
    int e = base + r * 256 + t;
    if (e < E) {
      src[r] = ei[e];
      dst[r] = ei[(size_t)E + e];
      atomicAdd(&lh[dst[r] >> 8], 1);
    } else {
      dst[r] = -1;
    }
  }
  __syncthreads();
  for (int i = t; i < 1024; i += 256) {
    int c = lh[i];
    lbase[i] = c ? atomicAdd(&bcur[i], c) : 0;
    lh[i] = 0;
  }
  __syncthreads();
#pragma unroll
  for (int r = 0; r < 16; ++r) {
    if (dst[r] >= 0) {
      int b = dst[r] >> 8;
      int rank = atomicAdd(&lh[b], 1);
      ebuf[lbase[b] + rank] = make_int2(src[r], dst[r]);
    }
  }
}

__global__ void fine_kernel(const int* __restrict__ bbase, const int2* __restrict__ ebuf,
                            int* __restrict__ row_ptr, int* __restrict__ col, int E, int N,
                            int K) {
  int bkt = blockIdx.x;
  int nb0 = bkt << 8;
  int t = threadIdx.x;  // 256
  int base = bbase[bkt];
  int endi = (bkt + 1 < K) ? bbase[bkt + 1] : E;
  __shared__ int sdeg[256];
  __shared__ int cur[256];
  sdeg[t] = 0;
  __syncthreads();
  for (int i = base + t; i < endi; i += 256) atomicAdd(&sdeg[ebuf[i].y & 255], 1);
  __syncthreads();
  int v = sdeg[t];
  int acc = v;
  for (int d = 1; d < 256; d <<= 1) {
    int add = (t >= d) ? sdeg[t - d] : 0;
    __syncthreads();
    acc += add;
    sdeg[t] = acc;
    __syncthreads();
  }
  int gp = base + (acc - v);  // exclusive prefix
  if (nb0 + t < N) row_ptr[nb0 + t] = gp;
  if (bkt == K - 1 && t == 0) row_ptr[N] = E;
  cur[t] = gp;
  __syncthreads();
  for (int i = base + t; i < endi; i += 256) {
    int2 sd = ebuf[i];
    int slot = atomicAdd(&cur[sd.y & 255], 1);
    col[slot] = sd.x;
  }
}

// ================= conversions =================

// x fp32 -> bf16 plane + fp8 e4m3 plane
__global__ void convx_kernel(const float* __restrict__ x, ushort* __restrict__ Xh,
                             unsigned* __restrict__ F8, int total4) {
  int i = blockIdx.x * 256 + threadIdx.x;
  if (i >= total4) return;
  float4 v = *(const float4*)(x + (size_t)i * 4);
  ushort4 h;
  h.x = f2bf(v.x);
  h.y = f2bf(v.y);
  h.z = f2bf(v.z);
  h.w = f2bf(v.w);
  *(ushort4*)(Xh + (size_t)i * 4) = h;
  unsigned r = __builtin_amdgcn_cvt_pk_fp8_f32(v.x, v.y, 0u, false);
  r = __builtin_amdgcn_cvt_pk_fp8_f32(v.z, v.w, r, true);
  F8[i] = r;
}

// W [128 out][128 k] fp32 -> swizzled fragment-native bf16 planes (hi, lo separate)
// dst(j,k) = (j>>4)*2048 + ((k>>3)*16 + (j&15))*8 + (k&7)
__global__ void wconv_kernel(const float* Wl0, const float* Wr0, const float* Wl1,
                             const float* Wr1, const float* Wl2, const float* Wr2,
                             ushort* __restrict__ Wp) {
  int m = blockIdx.y;  // 0..5
  const float* src = (m == 0) ? Wl0 : (m == 1) ? Wr0 : (m == 2) ? Wl1
                   : (m == 3) ? Wr1 : (m == 4) ? Wl2 : Wr2;
  int layer = m >> 1, part = m & 1;
  ushort* dh = Wp + layer * 65536 + part * 32768;
  ushort* dl = dh + 16384;
  int i = blockIdx.x * 256 + threadIdx.x;  // 0..4095
  int j = i >> 5;
  int k = (i & 31) * 4;
  float4 v = *(const float4*)(src + (size_t)j * 128 + k);
  int doff = ((j >> 4) << 11) + (((k >> 3) << 4) + (j & 15)) * 8 + (k & 7);
  ushort4 h, l;
  h.x = f2bf(v.x); l.x = f2bf(v.x - bf2f(h.x));
  h.y = f2bf(v.y); l.y = f2bf(v.y - bf2f(h.y));
  h.z = f2bf(v.z); l.z = f2bf(v.z - bf2f(h.z));
  h.w = f2bf(v.w); l.w = f2bf(v.w - bf2f(h.w));
  *(ushort4*)(dh + doff) = h;
  *(ushort4*)(dl + doff) = l;
}

// ================= mean aggregation (fp8 gather, 8-lane group per node, 8-deep) =================
// group g = tid>>3 owns node blockIdx*32+g; lane d = tid&7 covers dims d*16..d*16+15.
// Serial edge loop per group, 8-deep unrolled (64 rows in flight/wave); NO shuffles.

__global__ void aggr_kernel(const unsigned char* __restrict__ F, const int* __restrict__ row_ptr,
                            const int* __restrict__ col, ushort* __restrict__ Mh, int n) {
  int node = blockIdx.x * 32 + (threadIdx.x >> 3);
  int d0 = (threadIdx.x & 7) * 16;  // byte offset in 128B fp8 row == dim base
  int beg = 0, end = 0;
  if (node < n) {
    beg = row_ptr[node];
    end = row_ptr[node + 1];
  }
  f32x2 s2[8] = {};
  int e = beg;
  for (; e + 8 <= end; e += 8) {
    int c0 = col[e], c1 = col[e + 1], c2 = col[e + 2], c3 = col[e + 3];
    int c4 = col[e + 4], c5 = col[e + 5], c6 = col[e + 6], c7 = col[e + 7];
    uint4 u0 = *(const uint4*)(F + (size_t)c0 * 128 + d0);
    uint4 u1 = *(const uint4*)(F + (size_t)c1 * 128 + d0);
    uint4 u2 = *(const uint4*)(F + (size_t)c2 * 128 + d0);
    uint4 u3 = *(const uint4*)(F + (size_t)c3 * 128 + d0);
    uint4 u4 = *(const uint4*)(F + (size_t)c4 * 128 + d0);
    uint4 u5 = *(const uint4*)(F + (size_t)c5 * 128 + d0);
    uint4 u6 = *(const uint4*)(F + (size_t)c6 * 128 + d0);
    uint4 u7 = *(const uint4*)(F + (size_t)c7 * 128 + d0);
    acc16v(u0, s2);
    acc16v(u1, s2);
    acc16v(u2, s2);
    acc16v(u3, s2);
    acc16v(u4, s2);
    acc16v(u5, s2);
    acc16v(u6, s2);
    acc16v(u7, s2);
  }
  for (; e + 4 <= end; e += 4) {
    int c0 = col[e], c1 = col[e + 1], c2 = col[e + 2], c3 = col[e + 3];
    uint4 u0 = *(const uint4*)(F + (size_t)c0 * 128 + d0);
    uint4 u1 = *(const uint4*)(F + (size_t)c1 * 128 + d0);
    uint4 u2 = *(const uint4*)(F + (size_t)c2 * 128 + d0);
    uint4 u3 = *(const uint4*)(F + (size_t)c3 * 128 + d0);
    acc16v(u0, s2);
    acc16v(u1, s2);
    acc16v(u2, s2);
    acc16v(u3, s2);
  }
  for (; e < end; ++e) {
    uint4 u = *(const uint4*)(F + (size_t)col[e] * 128 + d0);
    acc16v(u, s2);
  }
  if (node < n) {
    int d = end - beg;
    float inv = 1.0f / (float)(d > 1 ? d : 1);
    bf16x8 o0, o1;
#pragma unroll
    for (int k = 0; k < 4; ++k) {
      o0[2 * k] = (short)f2bf(s2[k][0] * inv);
      o0[2 * k + 1] = (short)f2bf(s2[k][1] * inv);
      o1[2 * k] = (short)f2bf(s2[k + 4][0] * inv);
      o1[2 * k + 1] = (short)f2bf(s2[k + 4][1] * inv);
    }
    ushort* mp = Mh + (size_t)node * 128 + d0;  // d0 doubles as dim index
    *(bf16x8*)mp = o0;
    *(bf16x8*)(mp + 8) = o1;
  }
}

// ================= LDS-staged split-W MFMA GEMM (2-phase staging pipeline) =================
// H = relu(M @ Wl^T + X @ Wr^T + b); A bf16 (LDS-staged, XOR-swizzled);
// W split hi/lo swizzled fragment-native (L2-resident); 2 MFMA/product.
// Stage M then X; vmcnt(4)+barrier -> M-phase MFMAs while X still in flight;
// vmcnt(0)+barrier -> X-phase. Epilogue via LDS: dense bf16 (+optional fp8 mirror).

__global__ __launch_bounds__(256) void gemm_kernel(
    const ushort* __restrict__ Mh, const ushort* __restrict__ Xh,
    const ushort* __restrict__ Wp, const float* __restrict__ bias,
    ushort* __restrict__ Hh, unsigned char* __restrict__ F8, int n) {
  __shared__ char smem[32768];
  ushort* sM = (ushort*)smem;  // [64][128] swizzled content
  ushort* sX = sM + 8192;      // [64][128]
  int t = threadIdx.x;
  int lane = t & 63;
  int li = lane & 15, lg = lane >> 4;
  int w = t >> 6;
  int m0g = blockIdx.x * 64;
  int mw = (w >> 1) * 32;  // wave row offset (block-local)
  int n0 = (w & 1) * 64;

  // ---- stage M (first), then X: linear LDS dest + inverse-swizzled global source ----
  {
    int rowb = t >> 4, g = t & 15;
#pragma unroll
    for (int it = 0; it < 4; ++it) {
      int r = it * 16 + rowb;
      int srcrow = m0g + r;
      if (srcrow > n - 1) srcrow = n - 1;
      int sb = (g * 16) ^ ((r & 7) << 4);
      const char* gm = (const char*)Mh + (size_t)srcrow * 256 + sb;
      __builtin_amdgcn_global_load_lds(
          (const __attribute__((address_space(1))) void*)gm,
          (__attribute__((address_space(3))) void*)(sM + r * 128 + g * 8), 16, 0, 0);
    }
#pragma unroll
    for (int it = 0; it < 4; ++it) {
      int r = it * 16 + rowb;
      int srcrow = m0g + r;
      if (srcrow > n - 1) srcrow = n - 1;
      int sb = (g * 16) ^ ((r & 7) << 4);
      const char* gx = (const char*)Xh + (size_t)srcrow * 256 + sb;
      __builtin_amdgcn_global_load_lds(
          (const __attribute__((address_space(1))) void*)gx,
          (__attribute__((address_space(3))) void*)(sX + r * 128 + g * 8), 16, 0, 0);
    }
  }

  f32x4 acc[2][4] = {};

  // ---- phase 0: M ready (oldest 4 loads), X still in flight ----
  asm volatile("s_waitcnt vmcnt(4)" ::: "memory");
  __builtin_amdgcn_sched_barrier(0);
  __builtin_amdgcn_s_barrier();
  {
    const ushort* sA = sM;
    const ushort* Wb = Wp;
#pragma unroll
    for (int s = 0; s < 4; ++s) {
      int kg = s * 4 + lg;
      bf16x8 bh[4], bl[4];
#pragma unroll
      for (int nf = 0; nf < 4; ++nf) {
        const ushort* bp = Wb + (((n0 >> 4) + nf) << 11) + (kg * 16 + li) * 8;
        bh[nf] = *(const bf16x8*)bp;
        bl[nf] = *(const bf16x8*)(bp + 16384);
      }
      bf16x8 a[2];
#pragma unroll
      for (int mf = 0; mf < 2; ++mf) {
        int r = mw + mf * 16 + li;
        int kb = (kg * 16) ^ ((r & 7) << 4);  // swizzled read
        a[mf] = *(const bf16x8*)(sA + r * 128 + (kb >> 1));
      }
#pragma unroll
      for (int mf = 0; mf < 2; ++mf)
#pragma unroll
        for (int nf = 0; nf < 4; ++nf) {
          acc[mf][nf] =
              __builtin_amdgcn_mfma_f32_16x16x32_bf16(a[mf], bh[nf], acc[mf][nf], 0, 0, 0);
          acc[mf][nf] =
              __builtin_amdgcn_mfma_f32_16x16x32_bf16(a[mf], bl[nf], acc[mf][nf], 0, 0, 0);
        }
    }
  }

  // ---- phase 1: X ready ----
  asm volatile("s_waitcnt vmcnt(0)" ::: "memory");
  __builtin_amdgcn_sched_barrier(0);
  __builtin_amdgcn_s_barrier();
  {
    const ushort* sA = sX;
    const ushort* Wb = Wp + 32768;
#pragma unroll
    for (int s = 0; s < 4; ++s) {
      int kg = s * 4 + lg;
      bf16x8 bh[4], bl[4];
#pragma unroll
      for (int nf = 0; nf < 4; ++nf) {
        const ushort* bp = Wb + (((n0 >> 4) + nf) << 11) + (kg * 16 + li) * 8;
        bh[nf] = *(const bf16x8*)bp;
        bl[nf] = *(const bf16x8*)(bp + 16384);
      }
      bf16x8 a[2];
#pragma unroll
      for (int mf = 0; mf < 2; ++mf) {
        int r = mw + mf * 16 + li;
        int kb = (kg * 16) ^ ((r & 7) << 4);
        a[mf] = *(const bf16x8*)(sA + r * 128 + (kb >> 1));
      }
#pragma unroll
      for (int mf = 0; mf < 2; ++mf)
#pragma unroll
        for (int nf = 0; nf < 4; ++nf) {
          acc[mf][nf] =
              __builtin_amdgcn_mfma_f32_16x16x32_bf16(a[mf], bh[nf], acc[mf][nf], 0, 0, 0);
          acc[mf][nf] =
              __builtin_amdgcn_mfma_f32_16x16x32_bf16(a[mf], bl[nf], acc[mf][nf], 0, 0, 0);
        }
    }
  }

  __syncthreads();  // A-tile reads done; reuse smem for output staging

  ushort* sO = (ushort*)smem;  // [64][128]
#pragma unroll
  for (int nf = 0; nf < 4; ++nf) {
    int c = n0 + nf * 16 + li;
    float bj = bias[c];
#pragma unroll
    for (int mf = 0; mf < 2; ++mf)
#pragma unroll
      for (int r = 0; r < 4; ++r) {
        int rl = mw + mf * 16 + lg * 4 + r;
        sO[rl * 128 + c] = f2bf(fmaxf(acc[mf][nf][r] + bj, 0.f));
      }
  }
  __syncthreads();
  // dense bf16 stores
  {
    int rowb = t >> 4, g = t & 15;
#pragma unroll
    for (int it = 0; it < 4; ++it) {
      int r = it * 16 + rowb;
      if (m0g + r < n)
        *(uint4*)(Hh + (size_t)(m0g + r) * 128 + g * 8) = *(const uint4*)(sO + r * 128 + g * 8);
    }
  }
  // dense fp8 mirror plane (for next layer's gather)
  if (F8) {
    int row = t >> 2, seg = t & 3;  // 4 threads x 32B per 128B row
    const ushort* srcp = sO + row * 128 + seg * 32;
    unsigned o[8];
#pragma unroll
    for (int j = 0; j < 8; ++j) {
      unsigned r = __builtin_amdgcn_cvt_pk_fp8_f32(bf2f(srcp[j * 4 + 0]), bf2f(srcp[j * 4 + 1]),
                                                   0u, false);
      r = __builtin_amdgcn_cvt_pk_fp8_f32(bf2f(srcp[j * 4 + 2]), bf2f(srcp[j * 4 + 3]), r, true);
      o[j] = r;
    }
    if (m0g + row < n) {
      unsigned char* dp = F8 + (size_t)(m0g + row) * 128 + seg * 32;
      *(uint4*)dp = make_uint4(o[0], o[1], o[2], o[3]);
      *(uint4*)(dp + 16) = make_uint4(o[4], o[5], o[6], o[7]);
    }
  }
}

// ================= global mean pool (boundary-based, bf16 input, no atomics) =================

__global__ void gbound_kernel(const int* __restrict__ batch, int* __restrict__ gstart, int n,
                              int G) {
  int i = blockIdx.x * 256 + threadIdx.x;
  if (i >= n) return;
  int b = batch[i];
  if (i == 0) {
    for (int g = 0; g <= b; ++g) gstart[g] = 0;
  } else {
    int p = batch[i - 1];
    for (int g = p + 1; g <= b; ++g) gstart[g] = i;
  }
  if (i == n - 1) {
    for (int g = b + 1; g <= G; ++g) gstart[g] = n;
  }
}

// one block per graph; 256 thr = 16 rowgroups x 16 dim-octets (bf16x8 loads)
__global__ __launch_bounds__(256) void pool2_kernel(const ushort* __restrict__ H,
                                                    const int* __restrict__ gstart,
                                                    float* __restrict__ out) {
  int g = blockIdx.x;
  int t = threadIdx.x;
  int d8 = t & 15;  // dim octet
  int ro = t >> 4;  // row group
  int beg = gstart[g], end = gstart[g + 1];
  float acc[8] = {};
#pragma unroll 2
  for (int r = beg + ro; r < end; r += 16) {
    bf16x8 v = *(const bf16x8*)(H + (size_t)r * 128 + d8 * 8);
#pragma unroll
    for (int k = 0; k < 8; ++k) acc[k] += bf2f((ushort)v[k]);
  }
  __shared__ float sred[16][128];
#pragma unroll
  for (int k = 0; k < 8; ++k) sred[ro][d8 * 8 + k] = acc[k];
  __syncthreads();
  if (t < 128) {
    float s = 0.f;
#pragma unroll
    for (int r = 0; r < 16; ++r) s += sred[r][t];
    int cnt = end - beg;
    out[(size_t)g * 128 + t] = s / (float)(cnt > 1 ? cnt : 1);
  }
}

// ================= host =================

extern "C" void kernel_launch(void* const* d_in, const int* in_sizes, int n_in,
                              void* d_out, int out_size, void* d_ws, size_t ws_size,
                              hipStream_t stream) {
  const float* x = (const float*)d_in[0];
  const int* ei = (const int*)d_in[1];
  const int* batch = (const int*)d_in[2];
  const float* Wl0 = (const float*)d_in[3];
  const float* Wr0 = (const float*)d_in[4];
  const float* b0 = (const float*)d_in[5];
  const float* Wl1 = (const float*)d_in[6];
  const float* Wr1 = (const float*)d_in[7];
  const float* b1 = (const float*)d_in[8];
  const float* Wl2 = (const float*)d_in[9];
  const float* Wr2 = (const float*)d_in[10];
  const float* b2 = (const float*)d_in[11];
  float* out = (float*)d_out;

  const int N = in_sizes[0] / 128;
  const int E = in_sizes[1] / 2;
  const int G = out_size / 128;
  const int K = (N + 255) >> 8;
  const size_t NF = (size_t)N * 128;

  char* ws = (char*)d_ws;
  size_t off = 0;
  auto carve = [&](size_t bytes) {
    size_t o = align_up(off, 512);
    off = o + bytes;
    return (void*)(ws + o);
  };
  int* row_ptr = (int*)carve(((size_t)N + 1) * 4);
  int* bcnt = (int*)carve(1024 * 4);
  int* bbase = (int*)carve(1024 * 4);
  int* bcur = (int*)carve(1024 * 4);
  int* gstart = (int*)carve(((size_t)G + 1) * 4);
  int* col = (int*)carve((size_t)E * 4);
  ushort* P0 = (ushort*)carve(NF * 2);  // bf16 feature planes
  ushort* P1 = (ushort*)carve(NF * 2);
  unsigned char* F0 = (unsigned char*)carve(NF);  // fp8 mirror planes
  unsigned char* F1 = (unsigned char*)carve(NF);
  ushort* M = (ushort*)carve(NF * 2);  // aggregated means (bf16)
  ushort* Wp = (ushort*)carve(3 * 65536 * 2);
  (void)ws_size;

  int2* ebuf = (int2*)M;  // ebuf (12.8MB) aliases M (25.6MB); dead before first aggr

  // ---- bucketed CSR build ----
  hipMemsetAsync(bcnt, 0, 1024 * 4, stream);
  int cgrid_e = (E + 4095) / 4096;
  hipLaunchKernelGGL(bhist_kernel, dim3(cgrid_e), dim3(256), 0, stream, ei, bcnt, E, K);
  hipLaunchKernelGGL(bscan_kernel, dim3(1), dim3(1024), 0, stream, bcnt, bbase, bcur, K);
  hipLaunchKernelGGL(bscatter_kernel, dim3(cgrid_e), dim3(256), 0, stream, ei, bcur, ebuf, E);
  hipLaunchKernelGGL(fine_kernel, dim3(K), dim3(256), 0, stream, bbase, ebuf, row_ptr, col, E, N,
                     K);

  // ---- conversions + graph bounds ----
  int cgrid = (int)((NF / 4 + 255) / 256);
  hipLaunchKernelGGL(convx_kernel, dim3(cgrid), dim3(256), 0, stream, x, P0, (unsigned*)F0,
                     (int)(NF / 4));
  hipLaunchKernelGGL(wconv_kernel, dim3(16, 6), dim3(256), 0, stream, Wl0, Wr0, Wl1, Wr1, Wl2,
                     Wr2, Wp);
  int ngrid = (N + 255) / 256;
  hipLaunchKernelGGL(gbound_kernel, dim3(ngrid), dim3(256), 0, stream, batch, gstart, N, G);

  int agrid = (N + 31) / 32;
  int ggrid = (N + 63) / 64;

  // ---- layer 0: gather F0(x) -> M; H0 -> P1 (bf16) + F1 (fp8) ----
  hipLaunchKernelGGL(aggr_kernel, dim3(agrid), dim3(256), 0, stream, F0, row_ptr, col, M, N);
  hipLaunchKernelGGL(gemm_kernel, dim3(ggrid), dim3(256), 0, stream, M, P0, Wp, b0, P1, F1, N);
  // ---- layer 1: gather F1(H0) -> M; H1 -> P0 (bf16) + F0 (fp8) ----
  hipLaunchKernelGGL(aggr_kernel, dim3(agrid), dim3(256), 0, stream, F1, row_ptr, col, M, N);
  hipLaunchKernelGGL(gemm_kernel, dim3(ggrid), dim3(256), 0, stream, M, P1, Wp + 65536, b1, P0,
                     F0, N);
  // ---- layer 2: gather F0(H1) -> M; H2 -> P1 (bf16, no fp8 mirror) ----
  hipLaunchKernelGGL(aggr_kernel, dim3(agrid), dim3(256), 0, stream, F0, row_ptr, col, M, N);
  hipLaunchKernelGGL(gemm_kernel, dim3(ggrid), dim3(256), 0, stream, M, P0, Wp + 2 * 65536, b2,
                     P1, (unsigned char*)nullptr, N);

  // ---- pool (bf16 input) ----
  hipLaunchKernelGGL(pool2_kernel, dim3(G), dim3(256), 0, stream, P1, gstart, out);
}

// Round 16
// 273.668 us; speedup vs baseline: 1.4575x; 1.4575x over previous
//
#include <hip/hip_runtime.h>

static inline size_t align_up(size_t x, size_t a) { return (x + a - 1) & ~(a - 1); }

using bf16x8 = __attribute__((ext_vector_type(8))) short;
using f32x4 = __attribute__((ext_vector_type(4))) float;
using f32x2 = __attribute__((ext_vector_type(2))) float;

__device__ inline ushort f2bf(float x) {  // RNE float->bf16
  unsigned u = __float_as_uint(x);
  return (ushort)((u + 0x7fffu + ((u >> 16) & 1u)) >> 16);
}
__device__ inline float bf2f(ushort h) { return __uint_as_float((unsigned)h << 16); }

// decode 4 fp8(e4m3) packed in a uint, accumulate into 2 f32x2 accumulators (v_pk_add_f32)
__device__ inline void acc4v(unsigned u, f32x2* s2) {
  s2[0] += __builtin_amdgcn_cvt_pk_f32_fp8(u, false);
  s2[1] += __builtin_amdgcn_cvt_pk_f32_fp8(u, true);
}
__device__ inline void acc16v(uint4 u, f32x2* s2) {
  acc4v(u.x, s2);
  acc4v(u.y, s2 + 2);
  acc4v(u.z, s2 + 4);
  acc4v(u.w, s2 + 6);
}

// ================= bucketed CSR build =================
// buckets of 256 consecutive dst nodes; K = ceil(N/256) (<=1024)

__global__ void bhist_kernel(const int* __restrict__ ei, int* __restrict__ bcnt, int E, int K) {
  __shared__ int lh[1024];
  int t = threadIdx.x;
  for (int i = t; i < 1024; i += 256) lh[i] = 0;
  __syncthreads();
  int base = blockIdx.x * 4096;
#pragma unroll
  for (int r = 0; r < 16; ++r) {
    int e = base + r * 256 + t;
    if (e < E) atomicAdd(&lh[ei[(size_t)E + e] >> 8], 1);
  }
  __syncthreads();
  for (int i = t; i < K; i += 256)
    if (lh[i]) atomicAdd(&bcnt[i], lh[i]);
}

__global__ void bscan_kernel(const int* __restrict__ bcnt, int* __restrict__ bbase,
                             int* __restrict__ bcur, int K) {
  __shared__ int sb[1024];
  int t = threadIdx.x;  // 1024
  int v = (t < K) ? bcnt[t] : 0;
  sb[t] = v;
  __syncthreads();
  int acc = v;
  for (int d = 1; d < 1024; d <<= 1) {
    int add = (t >= d) ? sb[t - d] : 0;
    __syncthreads();
    acc += add;
    sb[t] = acc;
    __syncthreads();
  }
  if (t < K) {
    int ex = acc - v;  // exclusive
    bbase[t] = ex;
    bcur[t] = ex;
  }
}

__global__ void bscatter_kernel(const int* __restrict__ ei, int* __restrict__ bcur,
                                int2* __restrict__ ebuf, int E) {
  __shared__ int lh[1024];
  __shared__ int lbase[1024];
  int t = threadIdx.x;
  for (int i = t; i < 1024; i += 256) lh[i] = 0;
  __syncthreads();
  int base = blockIdx.x * 4096;
  int src[16], dst[16];
#pragma unroll
  for (int r = 0; r < 16; ++r) {
    int e = base + r * 256 + t;
    if (e < E) {
      src[r] = ei[e];
      dst[r] = ei[(size_t)E + e];
      atomicAdd(&lh[dst[r] >> 8], 1);
    } else {
      dst[r] = -1;
    }
  }
  __syncthreads();
  for (int i = t; i < 1024; i += 256) {
    int c = lh[i];
    lbase[i] = c ? atomicAdd(&bcur[i], c) : 0;
    lh[i] = 0;
  }
  __syncthreads();
#pragma unroll
  for (int r = 0; r < 16; ++r) {
    if (dst[r] >= 0) {
      int b = dst[r] >> 8;
      int rank = atomicAdd(&lh[b], 1);
      ebuf[lbase[b] + rank] = make_int2(src[r], dst[r]);
    }
  }
}

__global__ void fine_kernel(const int* __restrict__ bbase, const int2* __restrict__ ebuf,
                            int* __restrict__ row_ptr, int* __restrict__ col, int E, int N,
                            int K) {
  int bkt = blockIdx.x;
  int nb0 = bkt << 8;
  int t = threadIdx.x;  // 256
  int base = bbase[bkt];
  int endi = (bkt + 1 < K) ? bbase[bkt + 1] : E;
  __shared__ int sdeg[256];
  __shared__ int cur[256];
  sdeg[t] = 0;
  __syncthreads();
  for (int i = base + t; i < endi; i += 256) atomicAdd(&sdeg[ebuf[i].y & 255], 1);
  __syncthreads();
  int v = sdeg[t];
  int acc = v;
  for (int d = 1; d < 256; d <<= 1) {
    int add = (t >= d) ? sdeg[t - d] : 0;
    __syncthreads();
    acc += add;
    sdeg[t] = acc;
    __syncthreads();
  }
  int gp = base + (acc - v);  // exclusive prefix
  if (nb0 + t < N) row_ptr[nb0 + t] = gp;
  if (bkt == K - 1 && t == 0) row_ptr[N] = E;
  cur[t] = gp;
  __syncthreads();
  for (int i = base + t; i < endi; i += 256) {
    int2 sd = ebuf[i];
    int slot = atomicAdd(&cur[sd.y & 255], 1);
    col[slot] = sd.x;
  }
}

// ================= conversions =================

// x fp32 -> bf16 plane + fp8 e4m3 plane
__global__ void convx_kernel(const float* __restrict__ x, ushort* __restrict__ Xh,
                             unsigned* __restrict__ F8, int total4) {
  int i = blockIdx.x * 256 + threadIdx.x;
  if (i >= total4) return;
  float4 v = *(const float4*)(x + (size_t)i * 4);
  ushort4 h;
  h.x = f2bf(v.x);
  h.y = f2bf(v.y);
  h.z = f2bf(v.z);
  h.w = f2bf(v.w);
  *(ushort4*)(Xh + (size_t)i * 4) = h;
  unsigned r = __builtin_amdgcn_cvt_pk_fp8_f32(v.x, v.y, 0u, false);
  r = __builtin_amdgcn_cvt_pk_fp8_f32(v.z, v.w, r, true);
  F8[i] = r;
}

// W [128 out][128 k] fp32 -> swizzled fragment-native bf16 planes (hi, lo separate)
// dst(j,k) = (j>>4)*2048 + ((k>>3)*16 + (j&15))*8 + (k&7)
__global__ void wconv_kernel(const float* Wl0, const float* Wr0, const float* Wl1,
                             const float* Wr1, const float* Wl2, const float* Wr2,
                             ushort* __restrict__ Wp) {
  int m = blockIdx.y;  // 0..5
  const float* src = (m == 0) ? Wl0 : (m == 1) ? Wr0 : (m == 2) ? Wl1
                   : (m == 3) ? Wr1 : (m == 4) ? Wl2 : Wr2;
  int layer = m >> 1, part = m & 1;
  ushort* dh = Wp + layer * 65536 + part * 32768;
  ushort* dl = dh + 16384;
  int i = blockIdx.x * 256 + threadIdx.x;  // 0..4095
  int j = i >> 5;
  int k = (i & 31) * 4;
  float4 v = *(const float4*)(src + (size_t)j * 128 + k);
  int doff = ((j >> 4) << 11) + (((k >> 3) << 4) + (j & 15)) * 8 + (k & 7);
  ushort4 h, l;
  h.x = f2bf(v.x); l.x = f2bf(v.x - bf2f(h.x));
  h.y = f2bf(v.y); l.y = f2bf(v.y - bf2f(h.y));
  h.z = f2bf(v.z); l.z = f2bf(v.z - bf2f(h.z));
  h.w = f2bf(v.w); l.w = f2bf(v.w - bf2f(h.w));
  *(ushort4*)(dh + doff) = h;
  *(ushort4*)(dl + doff) = l;
}

// ================= mean aggregation (fp8 gather, 8-lane group per node, 4-deep) =================
// group g = tid>>3 owns node blockIdx*32+g; lane d = tid&7 covers dims d*16..d*16+15.
// Serial edge loop per group, 4-deep unrolled (32 rows in flight/wave); NO shuffles.
// NOTE: 8-deep spilled (r15: VGPR 64, scratch writes 130MB, occupancy 34%) — keep 4-deep.

__global__ void aggr_kernel(const unsigned char* __restrict__ F, const int* __restrict__ row_ptr,
                            const int* __restrict__ col, ushort* __restrict__ Mh, int n) {
  int node = blockIdx.x * 32 + (threadIdx.x >> 3);
  int d0 = (threadIdx.x & 7) * 16;  // byte offset in 128B fp8 row == dim base
  int beg = 0, end = 0;
  if (node < n) {
    beg = row_ptr[node];
    end = row_ptr[node + 1];
  }
  f32x2 s2[8] = {};
  int e = beg;
  for (; e + 4 <= end; e += 4) {
    int c0 = col[e], c1 = col[e + 1], c2 = col[e + 2], c3 = col[e + 3];
    uint4 u0 = *(const uint4*)(F + (size_t)c0 * 128 + d0);
    uint4 u1 = *(const uint4*)(F + (size_t)c1 * 128 + d0);
    uint4 u2 = *(const uint4*)(F + (size_t)c2 * 128 + d0);
    uint4 u3 = *(const uint4*)(F + (size_t)c3 * 128 + d0);
    acc16v(u0, s2);
    acc16v(u1, s2);
    acc16v(u2, s2);
    acc16v(u3, s2);
  }
  for (; e < end; ++e) {
    uint4 u = *(const uint4*)(F + (size_t)col[e] * 128 + d0);
    acc16v(u, s2);
  }
  if (node < n) {
    int d = end - beg;
    float inv = 1.0f / (float)(d > 1 ? d : 1);
    bf16x8 o0, o1;
#pragma unroll
    for (int k = 0; k < 4; ++k) {
      o0[2 * k] = (short)f2bf(s2[k][0] * inv);
      o0[2 * k + 1] = (short)f2bf(s2[k][1] * inv);
      o1[2 * k] = (short)f2bf(s2[k + 4][0] * inv);
      o1[2 * k + 1] = (short)f2bf(s2[k + 4][1] * inv);
    }
    ushort* mp = Mh + (size_t)node * 128 + d0;  // d0 doubles as dim index
    *(bf16x8*)mp = o0;
    *(bf16x8*)(mp + 8) = o1;
  }
}

// ================= LDS-staged split-W MFMA GEMM (2-phase staging pipeline) =================
// H = relu(M @ Wl^T + X @ Wr^T + b); A bf16 (LDS-staged, XOR-swizzled);
// W split hi/lo swizzled fragment-native (L2-resident); 2 MFMA/product.
// Stage M then X; vmcnt(4)+barrier -> M-phase MFMAs while X still in flight;
// vmcnt(0)+barrier -> X-phase. Epilogue via LDS: dense bf16 (+optional fp8 mirror).

__global__ __launch_bounds__(256) void gemm_kernel(
    const ushort* __restrict__ Mh, const ushort* __restrict__ Xh,
    const ushort* __restrict__ Wp, const float* __restrict__ bias,
    ushort* __restrict__ Hh, unsigned char* __restrict__ F8, int n) {
  __shared__ char smem[32768];
  ushort* sM = (ushort*)smem;  // [64][128] swizzled content
  ushort* sX = sM + 8192;      // [64][128]
  int t = threadIdx.x;
  int lane = t & 63;
  int li = lane & 15, lg = lane >> 4;
  int w = t >> 6;
  int m0g = blockIdx.x * 64;
  int mw = (w >> 1) * 32;  // wave row offset (block-local)
  int n0 = (w & 1) * 64;

  // ---- stage M (first), then X: linear LDS dest + inverse-swizzled global source ----
  {
    int rowb = t >> 4, g = t & 15;
#pragma unroll
    for (int it = 0; it < 4; ++it) {
      int r = it * 16 + rowb;
      int srcrow = m0g + r;
      if (srcrow > n - 1) srcrow = n - 1;
      int sb = (g * 16) ^ ((r & 7) << 4);
      const char* gm = (const char*)Mh + (size_t)srcrow * 256 + sb;
      __builtin_amdgcn_global_load_lds(
          (const __attribute__((address_space(1))) void*)gm,
          (__attribute__((address_space(3))) void*)(sM + r * 128 + g * 8), 16, 0, 0);
    }
#pragma unroll
    for (int it = 0; it < 4; ++it) {
      int r = it * 16 + rowb;
      int srcrow = m0g + r;
      if (srcrow > n - 1) srcrow = n - 1;
      int sb = (g * 16) ^ ((r & 7) << 4);
      const char* gx = (const char*)Xh + (size_t)srcrow * 256 + sb;
      __builtin_amdgcn_global_load_lds(
          (const __attribute__((address_space(1))) void*)gx,
          (__attribute__((address_space(3))) void*)(sX + r * 128 + g * 8), 16, 0, 0);
    }
  }

  f32x4 acc[2][4] = {};

  // ---- phase 0: M ready (oldest 4 loads), X still in flight ----
  asm volatile("s_waitcnt vmcnt(4)" ::: "memory");
  __builtin_amdgcn_sched_barrier(0);
  __builtin_amdgcn_s_barrier();
  {
    const ushort* sA = sM;
    const ushort* Wb = Wp;
#pragma unroll
    for (int s = 0; s < 4; ++s) {
      int kg = s * 4 + lg;
      bf16x8 bh[4], bl[4];
#pragma unroll
      for (int nf = 0; nf < 4; ++nf) {
        const ushort* bp = Wb + (((n0 >> 4) + nf) << 11) + (kg * 16 + li) * 8;
        bh[nf] = *(const bf16x8*)bp;
        bl[nf] = *(const bf16x8*)(bp + 16384);
      }
      bf16x8 a[2];
#pragma unroll
      for (int mf = 0; mf < 2; ++mf) {
        int r = mw + mf * 16 + li;
        int kb = (kg * 16) ^ ((r & 7) << 4);  // swizzled read
        a[mf] = *(const bf16x8*)(sA + r * 128 + (kb >> 1));
      }
#pragma unroll
      for (int mf = 0; mf < 2; ++mf)
#pragma unroll
        for (int nf = 0; nf < 4; ++nf) {
          acc[mf][nf] =
              __builtin_amdgcn_mfma_f32_16x16x32_bf16(a[mf], bh[nf], acc[mf][nf], 0, 0, 0);
          acc[mf][nf] =
              __builtin_amdgcn_mfma_f32_16x16x32_bf16(a[mf], bl[nf], acc[mf][nf], 0, 0, 0);
        }
    }
  }

  // ---- phase 1: X ready ----
  asm volatile("s_waitcnt vmcnt(0)" ::: "memory");
  __builtin_amdgcn_sched_barrier(0);
  __builtin_amdgcn_s_barrier();
  {
    const ushort* sA = sX;
    const ushort* Wb = Wp + 32768;
#pragma unroll
    for (int s = 0; s < 4; ++s) {
      int kg = s * 4 + lg;
      bf16x8 bh[4], bl[4];
#pragma unroll
      for (int nf = 0; nf < 4; ++nf) {
        const ushort* bp = Wb + (((n0 >> 4) + nf) << 11) + (kg * 16 + li) * 8;
        bh[nf] = *(const bf16x8*)bp;
        bl[nf] = *(const bf16x8*)(bp + 16384);
      }
      bf16x8 a[2];
#pragma unroll
      for (int mf = 0; mf < 2; ++mf) {
        int r = mw + mf * 16 + li;
        int kb = (kg * 16) ^ ((r & 7) << 4);
        a[mf] = *(const bf16x8*)(sA + r * 128 + (kb >> 1));
      }
#pragma unroll
      for (int mf = 0; mf < 2; ++mf)
#pragma unroll
        for (int nf = 0; nf < 4; ++nf) {
          acc[mf][nf] =
              __builtin_amdgcn_mfma_f32_16x16x32_bf16(a[mf], bh[nf], acc[mf][nf], 0, 0, 0);
          acc[mf][nf] =
              __builtin_amdgcn_mfma_f32_16x16x32_bf16(a[mf], bl[nf], acc[mf][nf], 0, 0, 0);
        }
    }
  }

  __syncthreads();  // A-tile reads done; reuse smem for output staging

  ushort* sO = (ushort*)smem;  // [64][128]
#pragma unroll
  for (int nf = 0; nf < 4; ++nf) {
    int c = n0 + nf * 16 + li;
    float bj = bias[c];
#pragma unroll
    for (int mf = 0; mf < 2; ++mf)
#pragma unroll
      for (int r = 0; r < 4; ++r) {
        int rl = mw + mf * 16 + lg * 4 + r;
        sO[rl * 128 + c] = f2bf(fmaxf(acc[mf][nf][r] + bj, 0.f));
      }
  }
  __syncthreads();
  // dense bf16 stores
  {
    int rowb = t >> 4, g = t & 15;
#pragma unroll
    for (int it = 0; it < 4; ++it) {
      int r = it * 16 + rowb;
      if (m0g + r < n)
        *(uint4*)(Hh + (size_t)(m0g + r) * 128 + g * 8) = *(const uint4*)(sO + r * 128 + g * 8);
    }
  }
  // dense fp8 mirror plane (for next layer's gather)
  if (F8) {
    int row = t >> 2, seg = t & 3;  // 4 threads x 32B per 128B row
    const ushort* srcp = sO + row * 128 + seg * 32;
    unsigned o[8];
#pragma unroll
    for (int j = 0; j < 8; ++j) {
      unsigned r = __builtin_amdgcn_cvt_pk_fp8_f32(bf2f(srcp[j * 4 + 0]), bf2f(srcp[j * 4 + 1]),
                                                   0u, false);
      r = __builtin_amdgcn_cvt_pk_fp8_f32(bf2f(srcp[j * 4 + 2]), bf2f(srcp[j * 4 + 3]), r, true);
      o[j] = r;
    }
    if (m0g + row < n) {
      unsigned char* dp = F8 + (size_t)(m0g + row) * 128 + seg * 32;
      *(uint4*)dp = make_uint4(o[0], o[1], o[2], o[3]);
      *(uint4*)(dp + 16) = make_uint4(o[4], o[5], o[6], o[7]);
    }
  }
}

// ================= global mean pool (boundary-based, bf16 input, no atomics) =================

__global__ void gbound_kernel(const int* __restrict__ batch, int* __restrict__ gstart, int n,
                              int G) {
  int i = blockIdx.x * 256 + threadIdx.x;
  if (i >= n) return;
  int b = batch[i];
  if (i == 0) {
    for (int g = 0; g <= b; ++g) gstart[g] = 0;
  } else {
    int p = batch[i - 1];
    for (int g = p + 1; g <= b; ++g) gstart[g] = i;
  }
  if (i == n - 1) {
    for (int g = b + 1; g <= G; ++g) gstart[g] = n;
  }
}

// one block per graph; 256 thr = 16 rowgroups x 16 dim-octets (bf16x8 loads)
__global__ __launch_bounds__(256) void pool2_kernel(const ushort* __restrict__ H,
                                                    const int* __restrict__ gstart,
                                                    float* __restrict__ out) {
  int g = blockIdx.x;
  int t = threadIdx.x;
  int d8 = t & 15;  // dim octet
  int ro = t >> 4;  // row group
  int beg = gstart[g], end = gstart[g + 1];
  float acc[8] = {};
#pragma unroll 2
  for (int r = beg + ro; r < end; r += 16) {
    bf16x8 v = *(const bf16x8*)(H + (size_t)r * 128 + d8 * 8);
#pragma unroll
    for (int k = 0; k < 8; ++k) acc[k] += bf2f((ushort)v[k]);
  }
  __shared__ float sred[16][128];
#pragma unroll
  for (int k = 0; k < 8; ++k) sred[ro][d8 * 8 + k] = acc[k];
  __syncthreads();
  if (t < 128) {
    float s = 0.f;
#pragma unroll
    for (int r = 0; r < 16; ++r) s += sred[r][t];
    int cnt = end - beg;
    out[(size_t)g * 128 + t] = s / (float)(cnt > 1 ? cnt : 1);
  }
}

// ================= host =================

extern "C" void kernel_launch(void* const* d_in, const int* in_sizes, int n_in,
                              void* d_out, int out_size, void* d_ws, size_t ws_size,
                              hipStream_t stream) {
  const float* x = (const float*)d_in[0];
  const int* ei = (const int*)d_in[1];
  const int* batch = (const int*)d_in[2];
  const float* Wl0 = (const float*)d_in[3];
  const float* Wr0 = (const float*)d_in[4];
  const float* b0 = (const float*)d_in[5];
  const float* Wl1 = (const float*)d_in[6];
  const float* Wr1 = (const float*)d_in[7];
  const float* b1 = (const float*)d_in[8];
  const float* Wl2 = (const float*)d_in[9];
  const float* Wr2 = (const float*)d_in[10];
  const float* b2 = (const float*)d_in[11];
  float* out = (float*)d_out;

  const int N = in_sizes[0] / 128;
  const int E = in_sizes[1] / 2;
  const int G = out_size / 128;
  const int K = (N + 255) >> 8;
  const size_t NF = (size_t)N * 128;

  char* ws = (char*)d_ws;
  size_t off = 0;
  auto carve = [&](size_t bytes) {
    size_t o = align_up(off, 512);
    off = o + bytes;
    return (void*)(ws + o);
  };
  int* row_ptr = (int*)carve(((size_t)N + 1) * 4);
  int* bcnt = (int*)carve(1024 * 4);
  int* bbase = (int*)carve(1024 * 4);
  int* bcur = (int*)carve(1024 * 4);
  int* gstart = (int*)carve(((size_t)G + 1) * 4);
  int* col = (int*)carve((size_t)E * 4);
  ushort* P0 = (ushort*)carve(NF * 2);  // bf16 feature planes
  ushort* P1 = (ushort*)carve(NF * 2);
  unsigned char* F0 = (unsigned char*)carve(NF);  // fp8 mirror planes
  unsigned char* F1 = (unsigned char*)carve(NF);
  ushort* M = (ushort*)carve(NF * 2);  // aggregated means (bf16)
  ushort* Wp = (ushort*)carve(3 * 65536 * 2);
  (void)ws_size;

  int2* ebuf = (int2*)M;  // ebuf (12.8MB) aliases M (25.6MB); dead before first aggr

  // ---- bucketed CSR build ----
  hipMemsetAsync(bcnt, 0, 1024 * 4, stream);
  int cgrid_e = (E + 4095) / 4096;
  hipLaunchKernelGGL(bhist_kernel, dim3(cgrid_e), dim3(256), 0, stream, ei, bcnt, E, K);
  hipLaunchKernelGGL(bscan_kernel, dim3(1), dim3(1024), 0, stream, bcnt, bbase, bcur, K);
  hipLaunchKernelGGL(bscatter_kernel, dim3(cgrid_e), dim3(256), 0, stream, ei, bcur, ebuf, E);
  hipLaunchKernelGGL(fine_kernel, dim3(K), dim3(256), 0, stream, bbase, ebuf, row_ptr, col, E, N,
                     K);

  // ---- conversions + graph bounds ----
  int cgrid = (int)((NF / 4 + 255) / 256);
  hipLaunchKernelGGL(convx_kernel, dim3(cgrid), dim3(256), 0, stream, x, P0, (unsigned*)F0,
                     (int)(NF / 4));
  hipLaunchKernelGGL(wconv_kernel, dim3(16, 6), dim3(256), 0, stream, Wl0, Wr0, Wl1, Wr1, Wl2,
                     Wr2, Wp);
  int ngrid = (N + 255) / 256;
  hipLaunchKernelGGL(gbound_kernel, dim3(ngrid), dim3(256), 0, stream, batch, gstart, N, G);

  int agrid = (N + 31) / 32;
  int ggrid = (N + 63) / 64;

  // ---- layer 0: gather F0(x) -> M; H0 -> P1 (bf16) + F1 (fp8) ----
  hipLaunchKernelGGL(aggr_kernel, dim3(agrid), dim3(256), 0, stream, F0, row_ptr, col, M, N);
  hipLaunchKernelGGL(gemm_kernel, dim3(ggrid), dim3(256), 0, stream, M, P0, Wp, b0, P1, F1, N);
  // ---- layer 1: gather F1(H0) -> M; H1 -> P0 (bf16) + F0 (fp8) ----
  hipLaunchKernelGGL(aggr_kernel, dim3(agrid), dim3(256), 0, stream, F1, row_ptr, col, M, N);
  hipLaunchKernelGGL(gemm_kernel, dim3(ggrid), dim3(256), 0, stream, M, P1, Wp + 65536, b1, P0,
                     F0, N);
  // ---- layer 2: gather F0(H1) -> M; H2 -> P1 (bf16, no fp8 mirror) ----
  hipLaunchKernelGGL(aggr_kernel, dim3(agrid), dim3(256), 0, stream, F0, row_ptr, col, M, N);
  hipLaunchKernelGGL(gemm_kernel, dim3(ggrid), dim3(256), 0, stream, M, P0, Wp + 2 * 65536, b2,
                     P1, (unsigned char*)nullptr, N);

  // ---- pool (bf16 input) ----
  hipLaunchKernelGGL(pool2_kernel, dim3(G), dim3(256), 0, stream, P1, gstart, out);
}

// Round 17
// 259.375 us; speedup vs baseline: 1.5378x; 1.0551x over previous
//
#include <hip/hip_runtime.h>

static inline size_t align_up(size_t x, size_t a) { return (x + a - 1) & ~(a - 1); }

using bf16x8 = __attribute__((ext_vector_type(8))) short;
using f32x4 = __attribute__((ext_vector_type(4))) float;
using f32x2 = __attribute__((ext_vector_type(2))) float;

#define BCAP 8192  // fixed bucket capacity (avg 4092, 64-sigma margin)

__device__ inline ushort f2bf(float x) {  // RNE float->bf16
  unsigned u = __float_as_uint(x);
  return (ushort)((u + 0x7fffu + ((u >> 16) & 1u)) >> 16);
}
__device__ inline float bf2f(ushort h) { return __uint_as_float((unsigned)h << 16); }

// decode 4 fp8(e4m3) packed in a uint, accumulate into 2 f32x2 accumulators (v_pk_add_f32)
__device__ inline void acc4v(unsigned u, f32x2* s2) {
  s2[0] += __builtin_amdgcn_cvt_pk_f32_fp8(u, false);
  s2[1] += __builtin_amdgcn_cvt_pk_f32_fp8(u, true);
}
__device__ inline void acc16v(uint4 u, f32x2* s2) {
  acc4v(u.x, s2);
  acc4v(u.y, s2 + 2);
  acc4v(u.z, s2 + 4);
  acc4v(u.w, s2 + 6);
}

// ================= bucketed CSR build (fixed-capacity, 2 kernels) =================
// bucket = dst>>8; base = bkt*BCAP; edge packed as src | (dst&255)<<24

__global__ void bscatter_kernel(const int* __restrict__ ei, int* __restrict__ bcur,
                                unsigned* __restrict__ ebuf, int E) {
  __shared__ int lh[1024];
  __shared__ int lbase[1024];
  int t = threadIdx.x;
  for (int i = t; i < 1024; i += 256) lh[i] = 0;
  __syncthreads();
  int base = blockIdx.x * 4096;
  int src[16], dst[16];
#pragma unroll
  for (int r = 0; r < 16; ++r) {
    int e = base + r * 256 + t;
    if (e < E) {
      src[r] = ei[e];
      dst[r] = ei[(size_t)E + e];
      atomicAdd(&lh[dst[r] >> 8], 1);
    } else {
      dst[r] = -1;
    }
  }
  __syncthreads();
  for (int i = t; i < 1024; i += 256) {
    int c = lh[i];
    lbase[i] = c ? atomicAdd(&bcur[i], c) : 0;
    lh[i] = 0;
  }
  __syncthreads();
#pragma unroll
  for (int r = 0; r < 16; ++r) {
    if (dst[r] >= 0) {
      int b = dst[r] >> 8;
      int rank = atomicAdd(&lh[b], 1);
      ebuf[(size_t)b * BCAP + lbase[b] + rank] =
          (unsigned)src[r] | ((unsigned)(dst[r] & 255) << 24);
    }
  }
}

// per bucket: LDS deg hist + scan -> row_beg/deg; LDS-cursor scatter -> padded col
__global__ void fine_kernel(const int* __restrict__ bcur, const unsigned* __restrict__ ebuf,
                            int* __restrict__ row_beg, int* __restrict__ deg_arr,
                            int* __restrict__ col, int N) {
  int bkt = blockIdx.x;
  int nb0 = bkt << 8;
  int t = threadIdx.x;  // 256
  int base = bkt * BCAP;
  int endi = base + bcur[bkt];
  __shared__ int sdeg[256];
  __shared__ int cur[256];
  sdeg[t] = 0;
  __syncthreads();
  for (int i = base + t; i < endi; i += 256) atomicAdd(&sdeg[ebuf[i] >> 24], 1);
  __syncthreads();
  int v = sdeg[t];
  int acc = v;
  for (int d = 1; d < 256; d <<= 1) {
    int add = (t >= d) ? sdeg[t - d] : 0;
    __syncthreads();
    acc += add;
    sdeg[t] = acc;
    __syncthreads();
  }
  int gp = base + (acc - v);  // exclusive prefix within padded bucket
  if (nb0 + t < N) {
    row_beg[nb0 + t] = gp;
    deg_arr[nb0 + t] = v;
  }
  cur[t] = gp;
  __syncthreads();
  for (int i = base + t; i < endi; i += 256) {
    unsigned sd = ebuf[i];
    int slot = atomicAdd(&cur[sd >> 24], 1);
    col[slot] = (int)(sd & 0xFFFFFFu);
  }
}

// ================= conversions =================

// x fp32 -> bf16 plane + fp8 e4m3 plane
__global__ void convx_kernel(const float* __restrict__ x, ushort* __restrict__ Xh,
                             unsigned* __restrict__ F8, int total4) {
  int i = blockIdx.x * 256 + threadIdx.x;
  if (i >= total4) return;
  float4 v = *(const float4*)(x + (size_t)i * 4);
  ushort4 h;
  h.x = f2bf(v.x);
  h.y = f2bf(v.y);
  h.z = f2bf(v.z);
  h.w = f2bf(v.w);
  *(ushort4*)(Xh + (size_t)i * 4) = h;
  unsigned r = __builtin_amdgcn_cvt_pk_fp8_f32(v.x, v.y, 0u, false);
  r = __builtin_amdgcn_cvt_pk_fp8_f32(v.z, v.w, r, true);
  F8[i] = r;
}

// W [128 out][128 k] fp32 -> swizzled fragment-native bf16 planes (hi, lo separate)
// dst(j,k) = (j>>4)*2048 + ((k>>3)*16 + (j&15))*8 + (k&7)
__global__ void wconv_kernel(const float* Wl0, const float* Wr0, const float* Wl1,
                             const float* Wr1, const float* Wl2, const float* Wr2,
                             ushort* __restrict__ Wp) {
  int m = blockIdx.y;  // 0..5
  const float* src = (m == 0) ? Wl0 : (m == 1) ? Wr0 : (m == 2) ? Wl1
                   : (m == 3) ? Wr1 : (m == 4) ? Wl2 : Wr2;
  int layer = m >> 1, part = m & 1;
  ushort* dh = Wp + layer * 65536 + part * 32768;
  ushort* dl = dh + 16384;
  int i = blockIdx.x * 256 + threadIdx.x;  // 0..4095
  int j = i >> 5;
  int k = (i & 31) * 4;
  float4 v = *(const float4*)(src + (size_t)j * 128 + k);
  int doff = ((j >> 4) << 11) + (((k >> 3) << 4) + (j & 15)) * 8 + (k & 7);
  ushort4 h, l;
  h.x = f2bf(v.x); l.x = f2bf(v.x - bf2f(h.x));
  h.y = f2bf(v.y); l.y = f2bf(v.y - bf2f(h.y));
  h.z = f2bf(v.z); l.z = f2bf(v.z - bf2f(h.z));
  h.w = f2bf(v.w); l.w = f2bf(v.w - bf2f(h.w));
  *(ushort4*)(dh + doff) = h;
  *(ushort4*)(dl + doff) = l;
}

// ================= mean aggregation (fp8 gather, 8-lane group per node, 4-deep) =================
// group g = tid>>3 owns node blockIdx*32+g; lane d = tid&7 covers dims d*16..d*16+15.
// NOTE: 8-deep spilled (r15: VGPR 64, scratch 130MB, occ 34%) — keep 4-deep (28 VGPR).

__global__ void aggr_kernel(const unsigned char* __restrict__ F, const int* __restrict__ row_beg,
                            const int* __restrict__ deg_arr, const int* __restrict__ col,
                            ushort* __restrict__ Mh, int n) {
  int node = blockIdx.x * 32 + (threadIdx.x >> 3);
  int d0 = (threadIdx.x & 7) * 16;  // byte offset in 128B fp8 row == dim base
  int beg = 0, end = 0, dg = 0;
  if (node < n) {
    beg = row_beg[node];
    dg = deg_arr[node];
    end = beg + dg;
  }
  f32x2 s2[8] = {};
  int e = beg;
  for (; e + 4 <= end; e += 4) {
    int c0 = col[e], c1 = col[e + 1], c2 = col[e + 2], c3 = col[e + 3];
    uint4 u0 = *(const uint4*)(F + (size_t)c0 * 128 + d0);
    uint4 u1 = *(const uint4*)(F + (size_t)c1 * 128 + d0);
    uint4 u2 = *(const uint4*)(F + (size_t)c2 * 128 + d0);
    uint4 u3 = *(const uint4*)(F + (size_t)c3 * 128 + d0);
    acc16v(u0, s2);
    acc16v(u1, s2);
    acc16v(u2, s2);
    acc16v(u3, s2);
  }
  for (; e < end; ++e) {
    uint4 u = *(const uint4*)(F + (size_t)col[e] * 128 + d0);
    acc16v(u, s2);
  }
  if (node < n) {
    float inv = 1.0f / (float)(dg > 1 ? dg : 1);
    bf16x8 o0, o1;
#pragma unroll
    for (int k = 0; k < 4; ++k) {
      o0[2 * k] = (short)f2bf(s2[k][0] * inv);
      o0[2 * k + 1] = (short)f2bf(s2[k][1] * inv);
      o1[2 * k] = (short)f2bf(s2[k + 4][0] * inv);
      o1[2 * k + 1] = (short)f2bf(s2[k + 4][1] * inv);
    }
    ushort* mp = Mh + (size_t)node * 128 + d0;  // d0 doubles as dim index
    *(bf16x8*)mp = o0;
    *(bf16x8*)(mp + 8) = o1;
  }
}

// ================= LDS-staged split-W MFMA GEMM (2-phase staging pipeline) =================
// H = relu(M @ Wl^T + X @ Wr^T + b); A bf16 (LDS-staged, XOR-swizzled);
// W split hi/lo swizzled fragment-native (L2-resident); 2 MFMA/product.
// Stage M then X; vmcnt(4)+barrier -> M-phase MFMAs while X still in flight;
// vmcnt(0)+barrier -> X-phase. Epilogue via LDS: dense bf16 (+optional fp8 mirror).

__global__ __launch_bounds__(256) void gemm_kernel(
    const ushort* __restrict__ Mh, const ushort* __restrict__ Xh,
    const ushort* __restrict__ Wp, const float* __restrict__ bias,
    ushort* __restrict__ Hh, unsigned char* __restrict__ F8, int n) {
  __shared__ char smem[32768];
  ushort* sM = (ushort*)smem;  // [64][128] swizzled content
  ushort* sX = sM + 8192;      // [64][128]
  int t = threadIdx.x;
  int lane = t & 63;
  int li = lane & 15, lg = lane >> 4;
  int w = t >> 6;
  int m0g = blockIdx.x * 64;
  int mw = (w >> 1) * 32;  // wave row offset (block-local)
  int n0 = (w & 1) * 64;

  // ---- stage M (first), then X: linear LDS dest + inverse-swizzled global source ----
  {
    int rowb = t >> 4, g = t & 15;
#pragma unroll
    for (int it = 0; it < 4; ++it) {
      int r = it * 16 + rowb;
      int srcrow = m0g + r;
      if (srcrow > n - 1) srcrow = n - 1;
      int sb = (g * 16) ^ ((r & 7) << 4);
      const char* gm = (const char*)Mh + (size_t)srcrow * 256 + sb;
      __builtin_amdgcn_global_load_lds(
          (const __attribute__((address_space(1))) void*)gm,
          (__attribute__((address_space(3))) void*)(sM + r * 128 + g * 8), 16, 0, 0);
    }
#pragma unroll
    for (int it = 0; it < 4; ++it) {
      int r = it * 16 + rowb;
      int srcrow = m0g + r;
      if (srcrow > n - 1) srcrow = n - 1;
      int sb = (g * 16) ^ ((r & 7) << 4);
      const char* gx = (const char*)Xh + (size_t)srcrow * 256 + sb;
      __builtin_amdgcn_global_load_lds(
          (const __attribute__((address_space(1))) void*)gx,
          (__attribute__((address_space(3))) void*)(sX + r * 128 + g * 8), 16, 0, 0);
    }
  }

  f32x4 acc[2][4] = {};

  // ---- phase 0: M ready (oldest 4 loads), X still in flight ----
  asm volatile("s_waitcnt vmcnt(4)" ::: "memory");
  __builtin_amdgcn_sched_barrier(0);
  __builtin_amdgcn_s_barrier();
  {
    const ushort* sA = sM;
    const ushort* Wb = Wp;
#pragma unroll
    for (int s = 0; s < 4; ++s) {
      int kg = s * 4 + lg;
      bf16x8 bh[4], bl[4];
#pragma unroll
      for (int nf = 0; nf < 4; ++nf) {
        const ushort* bp = Wb + (((n0 >> 4) + nf) << 11) + (kg * 16 + li) * 8;
        bh[nf] = *(const bf16x8*)bp;
        bl[nf] = *(const bf16x8*)(bp + 16384);
      }
      bf16x8 a[2];
#pragma unroll
      for (int mf = 0; mf < 2; ++mf) {
        int r = mw + mf * 16 + li;
        int kb = (kg * 16) ^ ((r & 7) << 4);  // swizzled read
        a[mf] = *(const bf16x8*)(sA + r * 128 + (kb >> 1));
      }
#pragma unroll
      for (int mf = 0; mf < 2; ++mf)
#pragma unroll
        for (int nf = 0; nf < 4; ++nf) {
          acc[mf][nf] =
              __builtin_amdgcn_mfma_f32_16x16x32_bf16(a[mf], bh[nf], acc[mf][nf], 0, 0, 0);
          acc[mf][nf] =
              __builtin_amdgcn_mfma_f32_16x16x32_bf16(a[mf], bl[nf], acc[mf][nf], 0, 0, 0);
        }
    }
  }

  // ---- phase 1: X ready ----
  asm volatile("s_waitcnt vmcnt(0)" ::: "memory");
  __builtin_amdgcn_sched_barrier(0);
  __builtin_amdgcn_s_barrier();
  {
    const ushort* sA = sX;
    const ushort* Wb = Wp + 32768;
#pragma unroll
    for (int s = 0; s < 4; ++s) {
      int kg = s * 4 + lg;
      bf16x8 bh[4], bl[4];
#pragma unroll
      for (int nf = 0; nf < 4; ++nf) {
        const ushort* bp = Wb + (((n0 >> 4) + nf) << 11) + (kg * 16 + li) * 8;
        bh[nf] = *(const bf16x8*)bp;
        bl[nf] = *(const bf16x8*)(bp + 16384);
      }
      bf16x8 a[2];
#pragma unroll
      for (int mf = 0; mf < 2; ++mf) {
        int r = mw + mf * 16 + li;
        int kb = (kg * 16) ^ ((r & 7) << 4);
        a[mf] = *(const bf16x8*)(sA + r * 128 + (kb >> 1));
      }
#pragma unroll
      for (int mf = 0; mf < 2; ++mf)
#pragma unroll
        for (int nf = 0; nf < 4; ++nf) {
          acc[mf][nf] =
              __builtin_amdgcn_mfma_f32_16x16x32_bf16(a[mf], bh[nf], acc[mf][nf], 0, 0, 0);
          acc[mf][nf] =
              __builtin_amdgcn_mfma_f32_16x16x32_bf16(a[mf], bl[nf], acc[mf][nf], 0, 0, 0);
        }
    }
  }

  __syncthreads();  // A-tile reads done; reuse smem for output staging

  ushort* sO = (ushort*)smem;  // [64][128]
#pragma unroll
  for (int nf = 0; nf < 4; ++nf) {
    int c = n0 + nf * 16 + li;
    float bj = bias[c];
#pragma unroll
    for (int mf = 0; mf < 2; ++mf)
#pragma unroll
      for (int r = 0; r < 4; ++r) {
        int rl = mw + mf * 16 + lg * 4 + r;
        sO[rl * 128 + c] = f2bf(fmaxf(acc[mf][nf][r] + bj, 0.f));
      }
  }
  __syncthreads();
  // dense bf16 stores
  {
    int rowb = t >> 4, g = t & 15;
#pragma unroll
    for (int it = 0; it < 4; ++it) {
      int r = it * 16 + rowb;
      if (m0g + r < n)
        *(uint4*)(Hh + (size_t)(m0g + r) * 128 + g * 8) = *(const uint4*)(sO + r * 128 + g * 8);
    }
  }
  // dense fp8 mirror plane (for next layer's gather)
  if (F8) {
    int row = t >> 2, seg = t & 3;  // 4 threads x 32B per 128B row
    const ushort* srcp = sO + row * 128 + seg * 32;
    unsigned o[8];
#pragma unroll
    for (int j = 0; j < 8; ++j) {
      unsigned r = __builtin_amdgcn_cvt_pk_fp8_f32(bf2f(srcp[j * 4 + 0]), bf2f(srcp[j * 4 + 1]),
                                                   0u, false);
      r = __builtin_amdgcn_cvt_pk_fp8_f32(bf2f(srcp[j * 4 + 2]), bf2f(srcp[j * 4 + 3]), r, true);
      o[j] = r;
    }
    if (m0g + row < n) {
      unsigned char* dp = F8 + (size_t)(m0g + row) * 128 + seg * 32;
      *(uint4*)dp = make_uint4(o[0], o[1], o[2], o[3]);
      *(uint4*)(dp + 16) = make_uint4(o[4], o[5], o[6], o[7]);
    }
  }
}

// ================= global mean pool (boundary-based, bf16 input, no atomics) =================

__global__ void gbound_kernel(const int* __restrict__ batch, int* __restrict__ gstart, int n,
                              int G) {
  int i = blockIdx.x * 256 + threadIdx.x;
  if (i >= n) return;
  int b = batch[i];
  if (i == 0) {
    for (int g = 0; g <= b; ++g) gstart[g] = 0;
  } else {
    int p = batch[i - 1];
    for (int g = p + 1; g <= b; ++g) gstart[g] = i;
  }
  if (i == n - 1) {
    for (int g = b + 1; g <= G; ++g) gstart[g] = n;
  }
}

// one block per graph; 256 thr = 16 rowgroups x 16 dim-octets (bf16x8 loads)
__global__ __launch_bounds__(256) void pool2_kernel(const ushort* __restrict__ H,
                                                    const int* __restrict__ gstart,
                                                    float* __restrict__ out) {
  int g = blockIdx.x;
  int t = threadIdx.x;
  int d8 = t & 15;  // dim octet
  int ro = t >> 4;  // row group
  int beg = gstart[g], end = gstart[g + 1];
  float acc[8] = {};
#pragma unroll 2
  for (int r = beg + ro; r < end; r += 16) {
    bf16x8 v = *(const bf16x8*)(H + (size_t)r * 128 + d8 * 8);
#pragma unroll
    for (int k = 0; k < 8; ++k) acc[k] += bf2f((ushort)v[k]);
  }
  __shared__ float sred[16][128];
#pragma unroll
  for (int k = 0; k < 8; ++k) sred[ro][d8 * 8 + k] = acc[k];
  __syncthreads();
  if (t < 128) {
    float s = 0.f;
#pragma unroll
    for (int r = 0; r < 16; ++r) s += sred[r][t];
    int cnt = end - beg;
    out[(size_t)g * 128 + t] = s / (float)(cnt > 1 ? cnt : 1);
  }
}

// ================= host =================

extern "C" void kernel_launch(void* const* d_in, const int* in_sizes, int n_in,
                              void* d_out, int out_size, void* d_ws, size_t ws_size,
                              hipStream_t stream) {
  const float* x = (const float*)d_in[0];
  const int* ei = (const int*)d_in[1];
  const int* batch = (const int*)d_in[2];
  const float* Wl0 = (const float*)d_in[3];
  const float* Wr0 = (const float*)d_in[4];
  const float* b0 = (const float*)d_in[5];
  const float* Wl1 = (const float*)d_in[6];
  const float* Wr1 = (const float*)d_in[7];
  const float* b1 = (const float*)d_in[8];
  const float* Wl2 = (const float*)d_in[9];
  const float* Wr2 = (const float*)d_in[10];
  const float* b2 = (const float*)d_in[11];
  float* out = (float*)d_out;

  const int N = in_sizes[0] / 128;
  const int E = in_sizes[1] / 2;
  const int G = out_size / 128;
  const int K = (N + 255) >> 8;
  const size_t NF = (size_t)N * 128;

  char* ws = (char*)d_ws;
  size_t off = 0;
  auto carve = [&](size_t bytes) {
    size_t o = align_up(off, 512);
    off = o + bytes;
    return (void*)(ws + o);
  };
  int* row_beg = (int*)carve((size_t)N * 4);
  int* deg_arr = (int*)carve((size_t)N * 4);
  int* bcur = (int*)carve(1024 * 4);
  int* gstart = (int*)carve(((size_t)G + 1) * 4);
  int* col = (int*)carve((size_t)K * BCAP * 4);       // padded col (12.8MB)
  unsigned* ebuf = (unsigned*)carve((size_t)K * BCAP * 4);  // packed edges (12.8MB)
  ushort* P0 = (ushort*)carve(NF * 2);  // bf16 feature planes
  ushort* P1 = (ushort*)carve(NF * 2);
  unsigned char* F0 = (unsigned char*)carve(NF);  // fp8 mirror planes
  unsigned char* F1 = (unsigned char*)carve(NF);
  ushort* M = (ushort*)carve(NF * 2);  // aggregated means (bf16)
  ushort* Wp = (ushort*)carve(3 * 65536 * 2);
  (void)ws_size;

  // ---- CSR build (fixed-capacity buckets) ----
  hipMemsetAsync(bcur, 0, 1024 * 4, stream);
  int cgrid_e = (E + 4095) / 4096;
  hipLaunchKernelGGL(bscatter_kernel, dim3(cgrid_e), dim3(256), 0, stream, ei, bcur, ebuf, E);
  hipLaunchKernelGGL(fine_kernel, dim3(K), dim3(256), 0, stream, bcur, ebuf, row_beg, deg_arr,
                     col, N);

  // ---- conversions + graph bounds ----
  int cgrid = (int)((NF / 4 + 255) / 256);
  hipLaunchKernelGGL(convx_kernel, dim3(cgrid), dim3(256), 0, stream, x, P0, (unsigned*)F0,
                     (int)(NF / 4));
  hipLaunchKernelGGL(wconv_kernel, dim3(16, 6), dim3(256), 0, stream, Wl0, Wr0, Wl1, Wr1, Wl2,
                     Wr2, Wp);
  int ngrid = (N + 255) / 256;
  hipLaunchKernelGGL(gbound_kernel, dim3(ngrid), dim3(256), 0, stream, batch, gstart, N, G);

  int agrid = (N + 31) / 32;
  int ggrid = (N + 63) / 64;

  // ---- layer 0: gather F0(x) -> M; H0 -> P1 (bf16) + F1 (fp8) ----
  hipLaunchKernelGGL(aggr_kernel, dim3(agrid), dim3(256), 0, stream, F0, row_beg, deg_arr, col,
                     M, N);
  hipLaunchKernelGGL(gemm_kernel, dim3(ggrid), dim3(256), 0, stream, M, P0, Wp, b0, P1, F1, N);
  // ---- layer 1: gather F1(H0) -> M; H1 -> P0 (bf16) + F0 (fp8) ----
  hipLaunchKernelGGL(aggr_kernel, dim3(agrid), dim3(256), 0, stream, F1, row_beg, deg_arr, col,
                     M, N);
  hipLaunchKernelGGL(gemm_kernel, dim3(ggrid), dim3(256), 0, stream, M, P1, Wp + 65536, b1, P0,
                     F0, N);
  // ---- layer 2: gather F0(H1) -> M; H2 -> P1 (bf16, no fp8 mirror) ----
  hipLaunchKernelGGL(aggr_kernel, dim3(agrid), dim3(256), 0, stream, F0, row_beg, deg_arr, col,
                     M, N);
  hipLaunchKernelGGL(gemm_kernel, dim3(ggrid), dim3(256), 0, stream, M, P0, Wp + 2 * 65536, b2,
                     P1, (unsigned char*)nullptr, N);

  // ---- pool (bf16 input) ----
  hipLaunchKernelGGL(pool2_kernel, dim3(G), dim3(256), 0, stream, P1, gstart, out);
}